// Round 2
// baseline (8623.746 us; speedup 1.0000x reference)
//
#include <hip/hip_runtime.h>
#include <math.h>

// SPINN forward, fp32 throughout (argmax trajectory sensitivity forbids bf16/f16).
// Persistent-kernel version: ONE kernel runs all 64 steps with device-wide epoch
// barriers between phases. Per step:
//   phase A: fused GEMM  [gates (K=1792,N=1024) || lstm5-sub (K=1024,N=2560)]
//   phase B: gates-reduce + LSTM + argmax + (reduce rows) track-GEMM + node + stack + next-X
// Barrier: monotonic epoch counter; arrive = fetch_add(1, RELEASE, agent) (flushes XCD L2),
// poll = fetch_add(0, RELAXED, agent) at LLC, exit fence = acquire/agent (invalidates L1/L2).

#define B_ 128
#define CAP 42
#define XW 2048   // X row: [buf_h 0:512 | s1_h 512:1024 | s2_h 1024:1536 | th_old 1536:1792 | pad]
#define GSPLIT 14 // gates k-splits, KS=128 (K=1792)
#define LSPLIT 8  // lstm5-sub k-splits, KS=128 (K=1024)
#define NBLK 544
#define NSTEP 64

__device__ __forceinline__ float sigm(float x) { return 1.f / (1.f + expf(-x)); }

__device__ __forceinline__ void gbar(unsigned* cnt, unsigned target) {
    __syncthreads();
    if (threadIdx.x == 0) {
        __hip_atomic_fetch_add(cnt, 1u, __ATOMIC_RELEASE, __HIP_MEMORY_SCOPE_AGENT);
        while (__hip_atomic_fetch_add(cnt, 0u, __ATOMIC_RELAXED, __HIP_MEMORY_SCOPE_AGENT) < target)
            __builtin_amdgcn_s_sleep(8);
        __builtin_amdgcn_fence(__ATOMIC_ACQUIRE, "agent");
    }
    __syncthreads();
}

// ---------------- repack weights ----------------
// W1T[k][n], k in [0,1792): k<1536 -> W_ih[n][k], else W_hh[n][k-1536].       N=1024
// W2T[k][n], k in [0,1024): k<512 -> W_right[n][k] (s1h), else W_left[n][k-512] (s2h). N=2560
// W3T[k][n], k in [0,256):  W_track[n][k].                                    N=2560
__global__ void k_repack(const float* __restrict__ W_ih, const float* __restrict__ W_hh,
                         const float* __restrict__ W_left, const float* __restrict__ W_right,
                         const float* __restrict__ W_track, const float* __restrict__ b_ih,
                         const float* __restrict__ b_hh,
                         float* __restrict__ W1T, float* __restrict__ W2T,
                         float* __restrict__ W3T, float* __restrict__ b1) {
    size_t idx = (size_t)blockIdx.x * 256 + threadIdx.x;
    const size_t n1 = 1792ull * 1024ull;   // 1,835,008
    const size_t n2 = 1024ull * 2560ull;   // 2,621,440
    const size_t n3 = 256ull * 2560ull;    //   655,360
    if (idx < n1) {
        int k = (int)(idx >> 10), n = (int)(idx & 1023);
        W1T[idx] = (k < 1536) ? W_ih[(size_t)n * 1536 + k] : W_hh[(size_t)n * 256 + (k - 1536)];
    } else if (idx < n1 + n2) {
        size_t r = idx - n1;
        int k = (int)(r / 2560), n = (int)(r % 2560);
        W2T[r] = (k < 512) ? W_right[(size_t)n * 512 + k] : W_left[(size_t)n * 512 + (k - 512)];
    } else if (idx < n1 + n2 + n3) {
        size_t r = idx - n1 - n2;
        int k = (int)(r / 2560), n = (int)(r % 2560);
        W3T[r] = W_track[(size_t)n * 256 + k];
    } else if (idx < n1 + n2 + n3 + 1024) {
        int i = (int)(idx - n1 - n2 - n3);
        b1[i] = b_ih[i] + b_hh[i];
    }
}

// ---------------- init state ----------------
__global__ void k_init(const float* __restrict__ buffers, float* __restrict__ stack,
                       float* __restrict__ X, float* __restrict__ tc,
                       int* __restrict__ sptr, int* __restrict__ blen,
                       unsigned* __restrict__ cnt) {
    int b = blockIdx.x, t = threadIdx.x;
    const float* b0 = buffers + (size_t)b * 40 * 1024;      // buffers[b][0]
    const float* btop = b0 + 39 * 1024;                     // buffers[b][39]
    float* stk = stack + (size_t)b * CAP * 1024;
    for (int j = t; j < 1024; j += 256) { stk[j] = b0[j]; stk[1024 + j] = b0[j]; }
    float* Xb = X + (size_t)b * XW;
    for (int j = t; j < 512; j += 256) {
        Xb[j] = btop[j]; Xb[512 + j] = b0[j]; Xb[1024 + j] = b0[j];
    }
    Xb[1536 + t] = 0.f;           // th_old = 0
    tc[b * 256 + t] = 0.f;
    if (t == 0) { sptr[b] = 2; blen[b] = 40; }
    if (b == 0 && t == 0) *cnt = 0u;
}

// ---------------- persistent kernel: 64 steps, 2 phases/step ----------------
// Phase A tiles (544): [0,224): gates ks=bid>>4, n0=(bid&15)*64, K-chunk 128, acol=k
//                      [224,544): lstm5 ks=b2/40, n0=(b2%40)*64, K-chunk 128, acol=512+k
// Phase B jobs (512): row b=bid>>2, slice q=bid&3; blocks >=512 idle.
__global__ __launch_bounds__(256, 3) void k_spinn(
        float* __restrict__ X,
        const float* __restrict__ W1T, const float* __restrict__ W2T,
        const float* __restrict__ W3T,
        float* __restrict__ gpart, float* __restrict__ lpart,
        const float* __restrict__ b1, const float* __restrict__ b_left,
        const float* __restrict__ W_trans, const float* __restrict__ b_trans,
        const float* __restrict__ buffers, float* __restrict__ stack,
        float* __restrict__ tc_a, float* __restrict__ tc_b,
        int* __restrict__ sp_a, int* __restrict__ sp_b,
        int* __restrict__ bl_a, int* __restrict__ bl_b,
        float* __restrict__ out, unsigned* cnt) {
    const int bid = blockIdx.x;
    const int tid = threadIdx.x;

    // ----- fixed phase-A tile assignment -----
    const float* WT; float* outp; int N, n0, k0, aoff;
    if (bid < 224) {
        int ks = bid >> 4, nb = bid & 15;
        WT = W1T; outp = gpart + (size_t)ks * 128 * 1024;
        N = 1024; n0 = nb * 64; k0 = ks * 128; aoff = 0;
    } else {
        int b2 = bid - 224; int ks = b2 / 40, nb = b2 % 40;
        WT = W2T; outp = lpart + (size_t)ks * 128 * 2560;
        N = 2560; n0 = nb * 64; k0 = ks * 128; aoff = 512;
    }
    const int tm = tid >> 4;      // 0..15
    const int tn = tid & 15;      // 0..15
    // ----- fixed phase-B job assignment -----
    const int brow = bid >> 2, q = bid & 3;

    __shared__ float As[32][132];
    __shared__ float Ws[32][68];
    __shared__ float sh_th[256];
    __shared__ float red[256][4];
    __shared__ float shg[5][132];

    unsigned epoch = 0;
    for (int s = 0; s < NSTEP; s++) {
        // ================= phase A: GEMM tile =================
        float acc[8][4];
#pragma unroll
        for (int i = 0; i < 8; i++)
#pragma unroll
            for (int j = 0; j < 4; j++) acc[i][j] = 0.f;

        for (int ki = 0; ki < 128; ki += 32) {
            const int kb = k0 + ki;
            __syncthreads();
            {   // stage A: As[kk][m] = X[m][aoff+kb+kk]
                int m = tid >> 1;
                int c8 = (tid & 1) * 16;
                const float4* src = (const float4*)(X + (size_t)m * XW + aoff + kb + c8);
#pragma unroll
                for (int j = 0; j < 4; j++) {
                    float4 v = src[j];
                    int kk = c8 + j * 4;
                    As[kk + 0][m] = v.x; As[kk + 1][m] = v.y; As[kk + 2][m] = v.z; As[kk + 3][m] = v.w;
                }
            }
            {   // stage W: Ws[kk][c..c+7] = WT[kb+kk][n0+c..]
                int kk = tid >> 3;
                int c = (tid & 7) * 8;
                const float4* src = (const float4*)(WT + (size_t)(kb + kk) * N + n0 + c);
                float4* dst = (float4*)(&Ws[kk][c]);
                dst[0] = src[0]; dst[1] = src[1];
            }
            __syncthreads();
#pragma unroll 4
            for (int kk = 0; kk < 32; kk++) {
                float a[8], w[4];
                *(float4*)&a[0] = *(const float4*)&As[kk][tm * 4];
                *(float4*)&a[4] = *(const float4*)&As[kk][64 + tm * 4];
                *(float4*)&w[0] = *(const float4*)&Ws[kk][tn * 4];
#pragma unroll
                for (int i = 0; i < 8; i++)
#pragma unroll
                    for (int j = 0; j < 4; j++) acc[i][j] += a[i] * w[j];
            }
        }
        {
            float* basep = outp + n0 + tn * 4;
#pragma unroll
            for (int i = 0; i < 8; i++) {
                int m = (i < 4) ? (tm * 4 + i) : (64 + tm * 4 + (i - 4));
                *(float4*)(basep + (size_t)m * N) = make_float4(acc[i][0], acc[i][1], acc[i][2], acc[i][3]);
            }
        }
        epoch++;
        gbar(cnt, (unsigned)NBLK * epoch);

        // ================= phase B =================
        if (bid < 512) {
            const float* tci = (s & 1) ? tc_b : tc_a;  float* tco = (s & 1) ? tc_a : tc_b;
            const int*   spi = (s & 1) ? sp_b : sp_a;  int*   spo = (s & 1) ? sp_a : sp_b;
            const int*   bli = (s & 1) ? bl_b : bl_a;  int*   blo = (s & 1) ? bl_a : bl_b;
            const int b = brow, t = tid;
            const int sp = spi[b], bl = bli[b];

            // 1) gather gates partials + LSTM cell
            const float* gp = gpart + (size_t)b * 1024;
            float gi = b1[t], gf = b1[256 + t], gg = b1[512 + t], go = b1[768 + t];
#pragma unroll
            for (int kc = 0; kc < GSPLIT; kc++) {
                const float* p = gp + (size_t)kc * 128 * 1024;
                gi += p[t]; gf += p[256 + t]; gg += p[512 + t]; go += p[768 + t];
            }
            float tcv = tci[b * 256 + t];
            float tcn = sigm(gf) * tcv + sigm(gi) * tanhf(gg);
            float thn = sigm(go) * tanhf(tcn);

            sh_th[t] = thn;
            red[t][0] = thn * W_trans[t];
            red[t][1] = thn * W_trans[256 + t];
            red[t][2] = thn * W_trans[512 + t];
            red[t][3] = thn * W_trans[768 + t];
            __syncthreads();
            for (int off = 128; off > 0; off >>= 1) {
                if (t < off) {
                    red[t][0] += red[t + off][0]; red[t][1] += red[t + off][1];
                    red[t][2] += red[t + off][2]; red[t][3] += red[t + off][3];
                }
                __syncthreads();
            }
            // 2) logits + first-max argmax (all threads identically)
            float lg[4]; int tr = 0; float best = -1e30f;
#pragma unroll
            for (int l = 0; l < 4; l++) {
                lg[l] = red[0][l] + b_trans[l];
                if (lg[l] > best) { best = lg[l]; tr = l; }
            }
            if (q == 0 && t == 0) {
                float* os = out + (size_t)s * B_ * 4;
#pragma unroll
                for (int l = 0; l < 4; l++) os[b * 4 + l] = lg[l];
            }
            const bool do_shift = (tr == 3) && (bl > 2);
            const bool do_red   = (tr == 2) && (sp > 3);
            const int spn = sp + (do_shift ? 1 : 0) - (do_red ? 1 : 0);
            const int bln = bl - (do_shift ? 1 : 0);
            float* stk = stack + (size_t)b * CAP * 1024;

            // 3) reduce rows: lstm5 = sub-partials + b_left + W_track@th_new ; node
            //    k-split across half-waves: kh=0 handles k<128 (+bias+partials 0..3),
            //    kh=1 handles k>=128 (+partials 4..7); combine via LDS.
            float node_h = 0.f;
            const int jj = t & 127, kh = t >> 7;
            if (do_red) {
                const int j = q * 128 + jj;
                float a, ii, f1, f2, oo;
                if (kh == 0) {
                    a  = b_left[j];        ii = b_left[512 + j]; f1 = b_left[1024 + j];
                    f2 = b_left[1536 + j]; oo = b_left[2048 + j];
                } else { a = ii = f1 = f2 = oo = 0.f; }
                const float* lp = lpart + (size_t)b * 2560;
#pragma unroll
                for (int kc = kh * 4; kc < kh * 4 + 4; kc++) {
                    const float* p = lp + (size_t)kc * 128 * 2560;
                    a += p[j]; ii += p[512 + j]; f1 += p[1024 + j]; f2 += p[1536 + j]; oo += p[2048 + j];
                }
                const float* w = W3T + j;
#pragma unroll 4
                for (int k = kh * 128; k < kh * 128 + 128; k++) {
                    float th = sh_th[k];
                    const float* wk = w + (size_t)k * 2560;
                    a += th * wk[0]; ii += th * wk[512]; f1 += th * wk[1024];
                    f2 += th * wk[1536]; oo += th * wk[2048];
                }
                if (kh == 1) {
                    shg[0][jj] = a; shg[1][jj] = ii; shg[2][jj] = f1; shg[3][jj] = f2; shg[4][jj] = oo;
                }
                __syncthreads();            // do_red is block-uniform
                if (kh == 0) {
                    a += shg[0][jj]; ii += shg[1][jj]; f1 += shg[2][jj];
                    f2 += shg[3][jj]; oo += shg[4][jj];
                    float s1c = stk[(size_t)(sp - 1) * 1024 + 512 + j];
                    float s2c = stk[(size_t)(sp - 2) * 1024 + 512 + j];
                    float c = tanhf(a) * sigm(ii) + sigm(f1) * s2c + sigm(f2) * s1c;
                    float h = sigm(oo) * tanhf(c);
                    stk[(size_t)(sp - 2) * 1024 + j] = h;          // own-slice addresses only
                    stk[(size_t)(sp - 2) * 1024 + 512 + j] = c;
                    node_h = h;
                }
            }
            // 4) shift: push buf_top (slot sp untouched by any read this step)
            if (do_shift) {
                const float* bt = buffers + ((size_t)b * 40 + (bl - 1)) * 1024;
                const int idx = q * 256 + t;
                stk[(size_t)sp * 1024 + idx] = bt[idx];
            }
            // 5) build next X (slice j = q*128 + t, t<128 i.e. kh==0)
            float* Xb = X + (size_t)b * XW;
            if (t < 128) {
                const int j = q * 128 + t;
                const float* btn = buffers + ((size_t)b * 40 + (bln - 1)) * 1024;
                Xb[j] = btn[j];                                 // buf_top' h
                float s1h;
                if (do_red)        s1h = node_h;                // just-built node (register)
                else if (do_shift) s1h = buffers[((size_t)b * 40 + (bl - 1)) * 1024 + j];
                else               s1h = stk[(size_t)(sp - 1) * 1024 + j];
                Xb[512 + j] = s1h;
                Xb[1024 + j] = stk[(size_t)(spn - 2) * 1024 + j];  // untouched slot in all 3 cases
            }
            if ((t >> 6) == q) {                                // th_old<-th_new, tc, sliced by q
                Xb[1536 + t] = thn;
                tco[b * 256 + t] = tcn;
            }
            if (q == 0 && t == 0) { spo[b] = spn; blo[b] = bln; }
        }
        epoch++;
        gbar(cnt, (unsigned)NBLK * epoch);
    }
}

// ---------------- host ----------------
extern "C" void kernel_launch(void* const* d_in, const int* in_sizes, int n_in,
                              void* d_out, int out_size, void* d_ws, size_t ws_size,
                              hipStream_t stream) {
    const float* buffers = (const float*)d_in[0];
    const float* W_left  = (const float*)d_in[1];
    const float* b_left  = (const float*)d_in[2];
    const float* W_right = (const float*)d_in[3];
    const float* W_track = (const float*)d_in[4];
    const float* W_ih    = (const float*)d_in[5];
    const float* W_hh    = (const float*)d_in[6];
    const float* b_ih    = (const float*)d_in[7];
    const float* b_hh    = (const float*)d_in[8];
    const float* W_trans = (const float*)d_in[9];
    const float* b_trans = (const float*)d_in[10];
    float* out = (float*)d_out;

    float* ws = (float*)d_ws;
    size_t off = 0;
    float* W1T   = ws + off; off += 1792ull * 1024;             // 1,835,008
    float* W2T   = ws + off; off += 1024ull * 2560;             // 2,621,440
    float* W3T   = ws + off; off += 256ull * 2560;              //   655,360
    float* b1    = ws + off; off += 1024;
    float* X     = ws + off; off += (size_t)B_ * XW;            //   262,144
    float* tc_a  = ws + off; off += (size_t)B_ * 256;
    float* tc_b  = ws + off; off += (size_t)B_ * 256;
    float* gpart = ws + off; off += (size_t)GSPLIT * B_ * 1024; // 1,835,008
    float* lpart = ws + off; off += (size_t)LSPLIT * B_ * 2560; // 2,621,440
    float* stack = ws + off; off += (size_t)B_ * CAP * 1024;    // 5,505,024
    int* sp_a = (int*)(ws + off); off += 128;
    int* sp_b = (int*)(ws + off); off += 128;
    int* bl_a = (int*)(ws + off); off += 128;
    int* bl_b = (int*)(ws + off); off += 128;
    unsigned* cnt = (unsigned*)(ws + off); off += 64;           // barrier counter (own cacheline)

    {
        size_t total = 1792ull * 1024 + 1024ull * 2560 + 256ull * 2560 + 1024;
        int blocks = (int)((total + 255) / 256);
        k_repack<<<blocks, 256, 0, stream>>>(W_ih, W_hh, W_left, W_right, W_track, b_ih, b_hh,
                                             W1T, W2T, W3T, b1);
        k_init<<<B_, 256, 0, stream>>>(buffers, stack, X, tc_a, sp_a, bl_a, cnt);
    }

    k_spinn<<<NBLK, 256, 0, stream>>>(X, W1T, W2T, W3T, gpart, lpart, b1, b_left,
                                      W_trans, b_trans, buffers, stack,
                                      tc_a, tc_b, sp_a, sp_b, bl_a, bl_b, out, cnt);
    (void)in_sizes; (void)n_in; (void)out_size; (void)ws_size;
}

// Round 3
// 3205.447 us; speedup vs baseline: 2.6903x; 2.6903x over previous
//
#include <hip/hip_runtime.h>
#include <math.h>

// SPINN forward, fp32 throughout (argmax trajectory sensitivity forbids bf16/f16).
// 3 launches/step (multi-launch beats persistent+fences on 8-XCD L2 coherence):
//   A (k_gemm, 544 blk): fused GEMM [gates (K=1792,N=1024) || lstm5-sub (K=1024,N=2560)]
//   M (k_mid, 128 blk):  gates-reduce (once) + LSTM + argmax + thn/tcn + decisions
//   C (k_node, 128 blk): tiled track-GEMM (W3T shared across rows via LDS) + TreeLSTM node
//                        + stack update + next-X build
// W3T traffic: fixed 21 MB/step (16x j-slice redundancy) vs 2.6 MB x n_reduce_rows before.

#define B_ 128
#define CAP 42
#define XW 2048   // X row: [buf_h 0:512 | s1_h 512:1024 | s2_h 1024:1536 | th_old 1536:1792 | pad]
#define GSPLIT 14 // gates k-splits, KS=128 (K=1792)
#define LSPLIT 8  // lstm5-sub k-splits, KS=128 (K=1024)
#define NSTEP 64

__device__ __forceinline__ float sigm(float x) { return 1.f / (1.f + expf(-x)); }

// ---------------- repack weights ----------------
// W1T[k][n], k in [0,1792): k<1536 -> W_ih[n][k], else W_hh[n][k-1536].       N=1024
// W2T[k][n], k in [0,1024): k<512 -> W_right[n][k] (s1h), else W_left[n][k-512] (s2h). N=2560
// W3T[k][n], k in [0,256):  W_track[n][k].                                    N=2560
__global__ void k_repack(const float* __restrict__ W_ih, const float* __restrict__ W_hh,
                         const float* __restrict__ W_left, const float* __restrict__ W_right,
                         const float* __restrict__ W_track, const float* __restrict__ b_ih,
                         const float* __restrict__ b_hh,
                         float* __restrict__ W1T, float* __restrict__ W2T,
                         float* __restrict__ W3T, float* __restrict__ b1) {
    size_t idx = (size_t)blockIdx.x * 256 + threadIdx.x;
    const size_t n1 = 1792ull * 1024ull;   // 1,835,008
    const size_t n2 = 1024ull * 2560ull;   // 2,621,440
    const size_t n3 = 256ull * 2560ull;    //   655,360
    if (idx < n1) {
        int k = (int)(idx >> 10), n = (int)(idx & 1023);
        W1T[idx] = (k < 1536) ? W_ih[(size_t)n * 1536 + k] : W_hh[(size_t)n * 256 + (k - 1536)];
    } else if (idx < n1 + n2) {
        size_t r = idx - n1;
        int k = (int)(r / 2560), n = (int)(r % 2560);
        W2T[r] = (k < 512) ? W_right[(size_t)n * 512 + k] : W_left[(size_t)n * 512 + (k - 512)];
    } else if (idx < n1 + n2 + n3) {
        size_t r = idx - n1 - n2;
        int k = (int)(r / 2560), n = (int)(r % 2560);
        W3T[r] = W_track[(size_t)n * 256 + k];
    } else if (idx < n1 + n2 + n3 + 1024) {
        int i = (int)(idx - n1 - n2 - n3);
        b1[i] = b_ih[i] + b_hh[i];
    }
}

// ---------------- init state ----------------
__global__ void k_init(const float* __restrict__ buffers, float* __restrict__ stack,
                       float* __restrict__ X, float* __restrict__ tc,
                       int* __restrict__ sptr, int* __restrict__ blen) {
    int b = blockIdx.x, t = threadIdx.x;
    const float* b0 = buffers + (size_t)b * 40 * 1024;      // buffers[b][0]
    const float* btop = b0 + 39 * 1024;                     // buffers[b][39]
    float* stk = stack + (size_t)b * CAP * 1024;
    for (int j = t; j < 1024; j += 256) { stk[j] = b0[j]; stk[1024 + j] = b0[j]; }
    float* Xb = X + (size_t)b * XW;
    for (int j = t; j < 512; j += 256) {
        Xb[j] = btop[j]; Xb[512 + j] = b0[j]; Xb[1024 + j] = b0[j];
    }
    Xb[1536 + t] = 0.f;           // th_old = 0
    tc[b * 256 + t] = 0.f;
    if (t == 0) { sptr[b] = 2; blen[b] = 40; }
}

// ---------------- A: fused tiled fp32 GEMM (gates || lstm5-sub), k-split partials ----------------
// blocks [0,224):  gates:  ks=bid>>4 (14), n0=(bid&15)*64,  K-chunk=[ks*128,+128), acol=k
// blocks [224,544): lstm5: ks=b2/40 (8),  n0=(b2%40)*64,   K-chunk=[ks*128,+128), acol=512+k
__global__ __launch_bounds__(256, 3) void k_gemm(const float* __restrict__ X,
                                                 const float* __restrict__ W1T,
                                                 const float* __restrict__ W2T,
                                                 float* __restrict__ gpart,
                                                 float* __restrict__ lpart) {
    __shared__ float As[32][132];
    __shared__ float Ws[32][68];
    const int bid = blockIdx.x;
    const float* WT; float* out; int N, n0, k0, aoff;
    if (bid < 224) {
        int ks = bid >> 4, nb = bid & 15;
        WT = W1T; out = gpart + (size_t)ks * 128 * 1024;
        N = 1024; n0 = nb * 64; k0 = ks * 128; aoff = 0;
    } else {
        int b2 = bid - 224; int ks = b2 / 40, nb = b2 % 40;
        WT = W2T; out = lpart + (size_t)ks * 128 * 2560;
        N = 2560; n0 = nb * 64; k0 = ks * 128; aoff = 512;
    }
    const int tid = threadIdx.x;
    const int tm = tid >> 4;      // 0..15
    const int tn = tid & 15;      // 0..15

    float acc[8][4];
#pragma unroll
    for (int i = 0; i < 8; i++)
#pragma unroll
        for (int j = 0; j < 4; j++) acc[i][j] = 0.f;

    for (int ki = 0; ki < 128; ki += 32) {
        const int kb = k0 + ki;
        __syncthreads();
        {   // stage A: As[kk][m] = X[m][aoff+kb+kk]
            int m = tid >> 1;
            int c8 = (tid & 1) * 16;
            const float4* src = (const float4*)(X + (size_t)m * XW + aoff + kb + c8);
#pragma unroll
            for (int j = 0; j < 4; j++) {
                float4 v = src[j];
                int kk = c8 + j * 4;
                As[kk + 0][m] = v.x; As[kk + 1][m] = v.y; As[kk + 2][m] = v.z; As[kk + 3][m] = v.w;
            }
        }
        {   // stage W: Ws[kk][c..c+7] = WT[kb+kk][n0+c..]
            int kk = tid >> 3;
            int c = (tid & 7) * 8;
            const float4* src = (const float4*)(WT + (size_t)(kb + kk) * N + n0 + c);
            float4* dst = (float4*)(&Ws[kk][c]);
            dst[0] = src[0]; dst[1] = src[1];
        }
        __syncthreads();
#pragma unroll 4
        for (int kk = 0; kk < 32; kk++) {
            float a[8], w[4];
            *(float4*)&a[0] = *(const float4*)&As[kk][tm * 4];
            *(float4*)&a[4] = *(const float4*)&As[kk][64 + tm * 4];
            *(float4*)&w[0] = *(const float4*)&Ws[kk][tn * 4];
#pragma unroll
            for (int i = 0; i < 8; i++)
#pragma unroll
                for (int j = 0; j < 4; j++) acc[i][j] += a[i] * w[j];
        }
    }
    float* base = out + n0 + tn * 4;
#pragma unroll
    for (int i = 0; i < 8; i++) {
        int m = (i < 4) ? (tm * 4 + i) : (64 + tm * 4 + (i - 4));
        *(float4*)(base + (size_t)m * N) = make_float4(acc[i][0], acc[i][1], acc[i][2], acc[i][3]);
    }
}

// ---------------- M: gates-reduce + LSTM + logits + argmax + decisions ----------------
__global__ __launch_bounds__(256) void k_mid(const float* __restrict__ gpart,
                                             const float* __restrict__ b1,
                                             const float* __restrict__ tc_in,
                                             float* __restrict__ tc_out,
                                             float* __restrict__ X,
                                             float* __restrict__ TH,
                                             const float* __restrict__ W_trans,
                                             const float* __restrict__ b_trans,
                                             const int* __restrict__ sp_in,
                                             int* __restrict__ sp_out,
                                             const int* __restrict__ bl_in,
                                             int* __restrict__ bl_out,
                                             int* __restrict__ dec,
                                             float* __restrict__ out_s) {
    int b = blockIdx.x, t = threadIdx.x;
    const float* gp = gpart + (size_t)b * 1024;
    float gi = b1[t], gf = b1[256 + t], gg = b1[512 + t], go = b1[768 + t];
#pragma unroll
    for (int kc = 0; kc < GSPLIT; kc++) {
        const float* p = gp + (size_t)kc * 128 * 1024;
        gi += p[t]; gf += p[256 + t]; gg += p[512 + t]; go += p[768 + t];
    }
    float tcv = tc_in[b * 256 + t];
    float tcn = sigm(gf) * tcv + sigm(gi) * tanhf(gg);
    float thn = sigm(go) * tanhf(tcn);
    tc_out[b * 256 + t] = tcn;
    TH[b * 256 + t] = thn;
    X[(size_t)b * XW + 1536 + t] = thn;     // th_old for next step's gates GEMM

    __shared__ float red[256][4];
    red[t][0] = thn * W_trans[t];
    red[t][1] = thn * W_trans[256 + t];
    red[t][2] = thn * W_trans[512 + t];
    red[t][3] = thn * W_trans[768 + t];
    __syncthreads();
    for (int off = 128; off > 0; off >>= 1) {
        if (t < off) {
            red[t][0] += red[t + off][0]; red[t][1] += red[t + off][1];
            red[t][2] += red[t + off][2]; red[t][3] += red[t + off][3];
        }
        __syncthreads();
    }
    if (t == 0) {
        float lg[4]; int tr = 0; float best = -1e30f;
#pragma unroll
        for (int l = 0; l < 4; l++) {
            lg[l] = red[0][l] + b_trans[l];
            if (lg[l] > best) { best = lg[l]; tr = l; }   // first-max like jnp.argmax
            out_s[b * 4 + l] = lg[l];
        }
        int sp = sp_in[b], bl = bl_in[b];
        int shv = (tr == 3 && bl > 2) ? 1 : 0;
        int rdv = (tr == 2 && sp > 3) ? 1 : 0;
        sp_out[b] = sp + shv - rdv;
        bl_out[b] = bl - shv;
        dec[b] = sp | (bl << 6) | (shv << 12) | (rdv << 13);
    }
}

// ---------------- C: tiled track-GEMM + TreeLSTM node + stack + next-X ----------------
// grid 128 = 16 j-slices (32 j each) x 8 rowgroups (16 rows). 256 thr = 16 rows x 16 jg (2 j each).
// Track GEMM K=256 staged: W3T chunk [32k][5g*32j] in LDS (20KB, reg-prefetched), TH [16][260] (16.6KB).
__global__ __launch_bounds__(256) void k_node(const float* __restrict__ lpart,
                                              const float* __restrict__ b_left,
                                              const float* __restrict__ W3T,
                                              const float* __restrict__ TH,
                                              const int* __restrict__ dec,
                                              const float* __restrict__ buffers,
                                              float* __restrict__ stack,
                                              float* __restrict__ X) {
    const int bid = blockIdx.x;
    const int jq = bid & 15, rg = bid >> 4;
    const int j0 = jq * 32, r0 = rg * 16;
    const int t = threadIdx.x;
    const int rl = t >> 4, jg = t & 15;
    const int row = r0 + rl;
    const int j = j0 + jg * 2;

    __shared__ float th_s[16 * 260];
    __shared__ float w_s[32 * 160];

    const int d = dec[row];
    const int sp = d & 63, bl = (d >> 6) & 63;
    const bool shv = (d >> 12) & 1, rdv = (d >> 13) & 1;
    const bool anyred = __any(rdv);

    // stage TH rows r0..r0+15 (stride 260 breaks 4-way bank aliasing on reads)
#pragma unroll
    for (int i = 0; i < 4; i++) {
        int L4 = i * 256 + t;               // float4 index in [0,1024)
        int rr = L4 >> 6, k4 = (L4 & 63) << 2;
        *(float4*)&th_s[rr * 260 + k4] = *(const float4*)(TH + (size_t)(r0 + rr) * 256 + k4);
    }

    float2 acc0 = {0,0}, acc1 = {0,0}, acc2 = {0,0}, acc3 = {0,0}, acc4 = {0,0};

    float4 pf[5];
#pragma unroll
    for (int i = 0; i < 5; i++) {           // prefetch chunk 0
        int L = i * 256 + t, seg = L >> 3, kk = seg / 5, g = seg - kk * 5, off = (L & 7) << 2;
        pf[i] = *(const float4*)(W3T + (size_t)kk * 2560 + g * 512 + j0 + off);
    }
    for (int kc = 0; kc < 8; kc++) {
#pragma unroll
        for (int i = 0; i < 5; i++) {
            int L = i * 256 + t, seg = L >> 3, kk = seg / 5, g = seg - kk * 5, off = (L & 7) << 2;
            *(float4*)&w_s[kk * 160 + g * 32 + off] = pf[i];
        }
        __syncthreads();
        if (kc < 7) {
#pragma unroll
            for (int i = 0; i < 5; i++) {   // prefetch next chunk during compute
                int L = i * 256 + t, seg = L >> 3, kk = seg / 5, g = seg - kk * 5, off = (L & 7) << 2;
                pf[i] = *(const float4*)(W3T + (size_t)((kc + 1) * 32 + kk) * 2560 + g * 512 + j0 + off);
            }
        }
        if (anyred) {
            const float* thp = &th_s[rl * 260 + kc * 32];
            const float* wp = &w_s[jg * 2];
#pragma unroll 8
            for (int kk = 0; kk < 32; kk++) {
                float th = thp[kk];
                const float* wr = wp + kk * 160;
                float2 w;
                w = *(const float2*)(wr);        acc0.x += th * w.x; acc0.y += th * w.y;
                w = *(const float2*)(wr + 32);   acc1.x += th * w.x; acc1.y += th * w.y;
                w = *(const float2*)(wr + 64);   acc2.x += th * w.x; acc2.y += th * w.y;
                w = *(const float2*)(wr + 96);   acc3.x += th * w.x; acc3.y += th * w.y;
                w = *(const float2*)(wr + 128);  acc4.x += th * w.x; acc4.y += th * w.y;
            }
        }
        __syncthreads();
    }

    float* stk = stack + (size_t)row * CAP * 1024;
    float* Xb = X + (size_t)row * XW;
    const int spn = sp + (shv ? 1 : 0) - (rdv ? 1 : 0);
    const int bln = bl - (shv ? 1 : 0);
    const float* bt = buffers + ((size_t)row * 40 + (bl - 1)) * 1024;

    float2 h2;
    if (rdv) {
        const float* lp = lpart + (size_t)row * 2560;
        float2 a  = *(const float2*)(b_left + j);
        float2 ii = *(const float2*)(b_left + 512 + j);
        float2 f1 = *(const float2*)(b_left + 1024 + j);
        float2 f2 = *(const float2*)(b_left + 1536 + j);
        float2 oo = *(const float2*)(b_left + 2048 + j);
#pragma unroll
        for (int kc = 0; kc < LSPLIT; kc++) {
            const float* p = lp + (size_t)kc * 128 * 2560;
            float2 v;
            v = *(const float2*)(p + j);        a.x += v.x;  a.y += v.y;
            v = *(const float2*)(p + 512 + j);  ii.x += v.x; ii.y += v.y;
            v = *(const float2*)(p + 1024 + j); f1.x += v.x; f1.y += v.y;
            v = *(const float2*)(p + 1536 + j); f2.x += v.x; f2.y += v.y;
            v = *(const float2*)(p + 2048 + j); oo.x += v.x; oo.y += v.y;
        }
        a.x += acc0.x; a.y += acc0.y;  ii.x += acc1.x; ii.y += acc1.y;
        f1.x += acc2.x; f1.y += acc2.y; f2.x += acc3.x; f2.y += acc3.y;
        oo.x += acc4.x; oo.y += acc4.y;
        float2 s1c = *(const float2*)(stk + (size_t)(sp - 1) * 1024 + 512 + j);
        float2 s2c = *(const float2*)(stk + (size_t)(sp - 2) * 1024 + 512 + j);
        float cx = tanhf(a.x) * sigm(ii.x) + sigm(f1.x) * s2c.x + sigm(f2.x) * s1c.x;
        float cy = tanhf(a.y) * sigm(ii.y) + sigm(f1.y) * s2c.y + sigm(f2.y) * s1c.y;
        h2.x = sigm(oo.x) * tanhf(cx); h2.y = sigm(oo.y) * tanhf(cy);
        *(float2*)(stk + (size_t)(sp - 2) * 1024 + j) = h2;
        *(float2*)(stk + (size_t)(sp - 2) * 1024 + 512 + j) = make_float2(cx, cy);
    } else if (shv) {
        h2 = *(const float2*)(bt + j);
    } else {
        h2 = *(const float2*)(stk + (size_t)(sp - 1) * 1024 + j);
    }
    *(float2*)(Xb + 512 + j) = h2;                              // s1' h
    if (shv) {                                                  // push buf_top at slot sp
        *(float2*)(stk + (size_t)sp * 1024 + j)       = *(const float2*)(bt + j);
        *(float2*)(stk + (size_t)sp * 1024 + 512 + j) = *(const float2*)(bt + 512 + j);
    }
    const float* btn = buffers + ((size_t)row * 40 + (bln - 1)) * 1024;
    *(float2*)(Xb + j) = *(const float2*)(btn + j);             // buf_top' h
    *(float2*)(Xb + 1024 + j) = *(const float2*)(stk + (size_t)(spn - 2) * 1024 + j);  // s2' h (untouched slot)
}

// ---------------- host ----------------
extern "C" void kernel_launch(void* const* d_in, const int* in_sizes, int n_in,
                              void* d_out, int out_size, void* d_ws, size_t ws_size,
                              hipStream_t stream) {
    const float* buffers = (const float*)d_in[0];
    const float* W_left  = (const float*)d_in[1];
    const float* b_left  = (const float*)d_in[2];
    const float* W_right = (const float*)d_in[3];
    const float* W_track = (const float*)d_in[4];
    const float* W_ih    = (const float*)d_in[5];
    const float* W_hh    = (const float*)d_in[6];
    const float* b_ih    = (const float*)d_in[7];
    const float* b_hh    = (const float*)d_in[8];
    const float* W_trans = (const float*)d_in[9];
    const float* b_trans = (const float*)d_in[10];
    float* out = (float*)d_out;

    float* ws = (float*)d_ws;
    size_t off = 0;
    float* W1T   = ws + off; off += 1792ull * 1024;             // 1,835,008
    float* W2T   = ws + off; off += 1024ull * 2560;             // 2,621,440
    float* W3T   = ws + off; off += 256ull * 2560;              //   655,360
    float* b1    = ws + off; off += 1024;
    float* X     = ws + off; off += (size_t)B_ * XW;            //   262,144
    float* tc_a  = ws + off; off += (size_t)B_ * 256;
    float* tc_b  = ws + off; off += (size_t)B_ * 256;
    float* TH    = ws + off; off += (size_t)B_ * 256;
    float* gpart = ws + off; off += (size_t)GSPLIT * B_ * 1024; // 1,835,008
    float* lpart = ws + off; off += (size_t)LSPLIT * B_ * 2560; // 2,621,440
    float* stack = ws + off; off += (size_t)B_ * CAP * 1024;    // 5,505,024
    int* sp_a = (int*)(ws + off); off += 128;
    int* sp_b = (int*)(ws + off); off += 128;
    int* bl_a = (int*)(ws + off); off += 128;
    int* bl_b = (int*)(ws + off); off += 128;
    int* dec  = (int*)(ws + off); off += 128;

    {
        size_t total = 1792ull * 1024 + 1024ull * 2560 + 256ull * 2560 + 1024;
        int blocks = (int)((total + 255) / 256);
        k_repack<<<blocks, 256, 0, stream>>>(W_ih, W_hh, W_left, W_right, W_track, b_ih, b_hh,
                                             W1T, W2T, W3T, b1);
        k_init<<<B_, 256, 0, stream>>>(buffers, stack, X, tc_a, sp_a, bl_a);
    }

    for (int s = 0; s < NSTEP; s++) {
        k_gemm<<<544, 256, 0, stream>>>(X, W1T, W2T, gpart, lpart);
        const float* tci = (s & 1) ? tc_b : tc_a;  float* tco = (s & 1) ? tc_a : tc_b;
        const int*   spi = (s & 1) ? sp_b : sp_a;  int*   spo = (s & 1) ? sp_a : sp_b;
        const int*   bli = (s & 1) ? bl_b : bl_a;  int*   blo = (s & 1) ? bl_a : bl_b;
        k_mid<<<B_, 256, 0, stream>>>(gpart, b1, tci, tco, X, TH, W_trans, b_trans,
                                      spi, spo, bli, blo, dec, out + (size_t)s * B_ * 4);
        k_node<<<128, 256, 0, stream>>>(lpart, b_left, W3T, TH, dec, buffers, stack, X);
    }
    (void)in_sizes; (void)n_in; (void)out_size; (void)ws_size;
}